// Round 8
// baseline (128.180 us; speedup 1.0000x reference)
//
#include <hip/hip_runtime.h>
#include <hip/hip_bf16.h>

typedef __bf16 bf16x8 __attribute__((ext_vector_type(8)));
typedef float f32x4 __attribute__((ext_vector_type(4)));
typedef unsigned short us8 __attribute__((ext_vector_type(8)));

#define MFMA16 __builtin_amdgcn_mfma_f32_16x16x32_bf16

__device__ __forceinline__ unsigned short f2bf(float f) {
    unsigned int u = __float_as_uint(f);
    u += 0x7fffu + ((u >> 16) & 1u);   // round-to-nearest-even
    return (unsigned short)(u >> 16);
}

__device__ __forceinline__ void gload_lds16(const void* g, void* l) {
    __builtin_amdgcn_global_load_lds(
        (const __attribute__((address_space(1))) unsigned int*)g,
        (__attribute__((address_space(3))) unsigned int*)l, 16, 0, 0);
}

// ============ Pass 1 (fused): pack A' = [x | h] along K' and B-hat panels ====
__global__ void cvt_all_kernel(const float* __restrict__ x, const float* __restrict__ h,
                               unsigned short* __restrict__ AP,
                               const float* __restrict__ W0, const float* __restrict__ W1,
                               const float* __restrict__ W2, const float* __restrict__ W3,
                               const float* __restrict__ W4, const float* __restrict__ W5,
                               unsigned short* __restrict__ WP) {
    if (blockIdx.x < 4096) {                         // x,h -> A'
        int c = blockIdx.x * 256 + threadIdx.x;      // 0 .. 2^20-1
        int ih = c >> 19;
        const float* src = ih ? h : x;
        int c2 = c & 524287;
        int mb = c2 >> 10, kb = (c2 >> 6) & 15, lane = c2 & 63;
        int r = lane & 15, ko = lane >> 4;
        const float* p = src + (size_t)(mb * 16 + r) * 512 + kb * 32 + ko * 8;
        float4 v0 = *(const float4*)p;
        float4 v1 = *(const float4*)(p + 4);
        us8 o = { f2bf(v0.x), f2bf(v0.y), f2bf(v0.z), f2bf(v0.w),
                  f2bf(v1.x), f2bf(v1.y), f2bf(v1.z), f2bf(v1.w) };
        *((us8*)AP + ((size_t)(mb * 32 + kb + ih * 16) << 6) + lane) = o;
    } else {                                          // weights -> B-hat
        int c = (blockIdx.x - 4096) * 256 + threadIdx.x;   // 0..196607
        int s = c >> 16, c2 = c & 65535;
        int frag = c2 >> 6, lane = c2 & 63;
        int nb = frag >> 5, kbp = frag & 31;
        const float* Wsrc;
        int kb;
        if (kbp < 16) { kb = kbp;      Wsrc = (s == 0) ? W0 : (s == 1) ? W2 : W4; }
        else          { kb = kbp - 16; Wsrc = (s == 0) ? W1 : (s == 1) ? W3 : W5; }
        int cc = lane & 15, ko = lane >> 4;
        int kbase = kb * 32 + ko * 8;
        us8 o;
#pragma unroll
        for (int e = 0; e < 8; ++e)
            o[e] = f2bf(Wsrc[(size_t)(kbase + e) * 512 + nb * 16 + cc]);
        *((us8*)WP + c) = o;
    }
}

// ============ Pass 2: ABLATION of the round-7 8-phase kernel ============
// V=0 FULL (correct, launched last)   V=1 NOSTAGE (no gload/vmcnt)
// V=2 NOBAR (no s_barriers)           V=3 SKELETON (MFMA stream only)
template<bool B> __device__ __forceinline__ void ph_end() {
    __builtin_amdgcn_s_setprio(0);
    if constexpr (B) __builtin_amdgcn_s_barrier();
}
template<bool B, bool D> __device__ __forceinline__ void ph_mid() {
    if constexpr (B) __builtin_amdgcn_s_barrier();
    if constexpr (D) asm volatile("s_waitcnt lgkmcnt(0)" ::: "memory");
    __builtin_amdgcn_sched_barrier(0);
    __builtin_amdgcn_s_setprio(1);
}
template<bool S, bool B> __device__ __forceinline__ void vmwait7() {
    if constexpr (S) asm volatile("s_waitcnt vmcnt(7)" ::: "memory");
    if constexpr (B) __builtin_amdgcn_s_barrier();
}
template<bool S, bool B> __device__ __forceinline__ void vmwait0() {
    if constexpr (S) asm volatile("s_waitcnt vmcnt(0)" ::: "memory");
    if constexpr (B) __builtin_amdgcn_s_barrier();
}

template<int V>
__global__ __launch_bounds__(512, 2) void augru_mm(
    const unsigned short* __restrict__ AP_,
    const unsigned short* __restrict__ WP_,
    const float* __restrict__ b_r, const float* __restrict__ b_u, const float* __restrict__ b_h,
    const float* __restrict__ att, const float* __restrict__ h32,
    float* __restrict__ out) {
    constexpr bool STAGE = (V == 0 || V == 2);
    constexpr bool BARS  = (V == 0 || V == 1);
    constexpr bool DSRD  = (V != 3);

    __shared__ unsigned char sL[2][57344];
    const unsigned char* AP  = (const unsigned char*)AP_;
    const unsigned char* WPb = (const unsigned char*)WP_;

    const int t = threadIdx.x, wv = t >> 6, lane = t & 63;
    const int laneoff = lane * 16;

    const int bid = blockIdx.x;                 // 0..255
    const int Wid = (bid & 7) * 32 + (bid >> 3);
    const int mblk = Wid >> 3, nblk = Wid & 7;
    const int wr = wv >> 1, wc = wv & 1;

    f32x4 accR[4][2] = {}, accU[4][2] = {}, accXH[4][2] = {}, accHH[4][2] = {};

    const unsigned char* gsrc[7];
    unsigned ldst[7];
#pragma unroll
    for (int i = 0; i < 4; ++i) {
        int f = i * 8 + wv, mbL = f >> 1, kq = f & 1;
        gsrc[i] = AP + ((size_t)((mblk * 16 + mbL) * 32 + kq) << 10) + laneoff;
        ldst[i] = (unsigned)f << 10;
    }
#pragma unroll
    for (int i = 4; i < 7; ++i) {
        int g = (i - 4) * 8 + wv, s = g >> 3, nbL = (g >> 1) & 3, kq = g & 1;
        gsrc[i] = WPb + (size_t)s * 1048576 +
                  ((size_t)((nblk * 4 + nbL) * 32 + kq) << 10) + laneoff;
        ldst[i] = 32768u + ((unsigned)g << 10);
    }

    unsigned aoff[4], boff[3][2];
#pragma unroll
    for (int mf = 0; mf < 4; ++mf) aoff[mf] = (((wr * 4 + mf) * 2) << 10) + laneoff;
#pragma unroll
    for (int s = 0; s < 3; ++s)
#pragma unroll
        for (int nf = 0; nf < 2; ++nf)
            boff[s][nf] = 32768u + (((s * 4 + wc * 2 + nf) * 2) << 10) + laneoff;

    // junk operand for SKELETON variant (one ds_read; DCE'd when DSRD)
    bf16x8 jA = *(const bf16x8*)&sL[0][laneoff];

#define ISSUE(TT, BI) { _Pragma("unroll") for (int i = 0; i < 7; ++i) \
        gload_lds16(gsrc[i] + ((size_t)(TT) << 11), &sL[BI][ldst[i]]); }

#define MM6(av, mf, nf, ACCC) \
    accR[mf][nf] = MFMA16(av, bRr[nf], accR[mf][nf], 0, 0, 0); \
    accU[mf][nf] = MFMA16(av, bUr[nf], accU[mf][nf], 0, 0, 0); \
    ACCC[mf][nf] = MFMA16(av, bCr[nf], ACCC[mf][nf], 0, 0, 0);

#define DO_TILE(BUFP, ACCC) { \
    const unsigned char* bufp = (BUFP); (void)bufp; \
    bf16x8 a0, a1, bRr[2], bUr[2], bCr[2]; \
    if constexpr (DSRD) { \
        a0 = *(const bf16x8*)(bufp + aoff[0]); a1 = *(const bf16x8*)(bufp + aoff[1]); \
        bRr[0] = *(const bf16x8*)(bufp + boff[0][0]); bRr[1] = *(const bf16x8*)(bufp + boff[0][1]); \
        bUr[0] = *(const bf16x8*)(bufp + boff[1][0]); bUr[1] = *(const bf16x8*)(bufp + boff[1][1]); \
        bCr[0] = *(const bf16x8*)(bufp + boff[2][0]); bCr[1] = *(const bf16x8*)(bufp + boff[2][1]); \
    } else { a0 = a1 = jA; bRr[0] = bRr[1] = jA; bUr[0] = bUr[1] = jA; bCr[0] = bCr[1] = jA; } \
    ph_mid<BARS, DSRD>(); MM6(a0, 0, 0, ACCC) MM6(a0, 0, 1, ACCC) \
                          MM6(a1, 1, 0, ACCC) MM6(a1, 1, 1, ACCC) ph_end<BARS>(); \
    if constexpr (DSRD) { a0 = *(const bf16x8*)(bufp + aoff[2]); a1 = *(const bf16x8*)(bufp + aoff[3]); } \
    ph_mid<BARS, DSRD>(); MM6(a0, 2, 0, ACCC) MM6(a0, 2, 1, ACCC) \
                          MM6(a1, 3, 0, ACCC) MM6(a1, 3, 1, ACCC) ph_end<BARS>(); \
    if constexpr (DSRD) { \
        a0 = *(const bf16x8*)(bufp + aoff[0] + 1024); a1 = *(const bf16x8*)(bufp + aoff[1] + 1024); \
        bRr[0] = *(const bf16x8*)(bufp + boff[0][0] + 1024); bRr[1] = *(const bf16x8*)(bufp + boff[0][1] + 1024); \
        bUr[0] = *(const bf16x8*)(bufp + boff[1][0] + 1024); bUr[1] = *(const bf16x8*)(bufp + boff[1][1] + 1024); \
        bCr[0] = *(const bf16x8*)(bufp + boff[2][0] + 1024); bCr[1] = *(const bf16x8*)(bufp + boff[2][1] + 1024); \
    } \
    ph_mid<BARS, DSRD>(); MM6(a0, 0, 0, ACCC) MM6(a0, 0, 1, ACCC) \
                          MM6(a1, 1, 0, ACCC) MM6(a1, 1, 1, ACCC) ph_end<BARS>(); \
    if constexpr (DSRD) { a0 = *(const bf16x8*)(bufp + aoff[2] + 1024); a1 = *(const bf16x8*)(bufp + aoff[3] + 1024); } \
    ph_mid<BARS, DSRD>(); MM6(a0, 2, 0, ACCC) MM6(a0, 2, 1, ACCC) \
                          MM6(a1, 3, 0, ACCC) MM6(a1, 3, 1, ACCC) ph_end<BARS>(); \
}

    if constexpr (STAGE) { ISSUE(0, 0) ISSUE(1, 1) }
    vmwait7<STAGE, BARS>();

#pragma unroll 1
    for (int tt = 0; tt < 8; ++tt) {            // x-half: C-set = xh
        DO_TILE(&sL[tt & 1][0], accXH)
        if constexpr (STAGE) ISSUE(tt + 2, tt & 1)
        vmwait7<STAGE, BARS>();
    }
#pragma unroll 1
    for (int tt = 8; tt < 14; ++tt) {           // h-half: C-set = hh
        DO_TILE(&sL[tt & 1][0], accHH)
        if constexpr (STAGE) ISSUE(tt + 2, tt & 1)
        vmwait7<STAGE, BARS>();
    }
    DO_TILE(&sL[0][0], accHH)                   // tile 14
    vmwait0<STAGE, BARS>();
    DO_TILE(&sL[1][0], accHH)                   // tile 15

    // epilogue: C/D layout col=lane&15, row=(lane>>4)*4+reg  [m89-verified]
    const int lr = lane & 15, lg = lane >> 4;
#pragma unroll
    for (int nf = 0; nf < 2; ++nf) {
        const int col = nblk * 64 + wc * 32 + nf * 16 + lr;
        const float br = b_r[col], bu = b_u[col], bh = b_h[col];
#pragma unroll
        for (int mf = 0; mf < 4; ++mf) {
            const int rowb = mblk * 256 + wr * 64 + mf * 16 + lg * 4;
#pragma unroll
            for (int q = 0; q < 4; ++q) {
                const int row = rowb + q;
                float r = 1.f / (1.f + __expf(-(accR[mf][nf][q] + br)));
                float u = 1.f / (1.f + __expf(-(accU[mf][nf][q] + bu)));
                float ph = accXH[mf][nf][q] + bh + r * accHH[mf][nf][q];
                ph = fminf(fmaxf(ph, -15.f), 15.f);
                float e = __expf(2.f * ph);
                float cal = (e - 1.f) / (e + 1.f);
                float hv = h32[(size_t)row * 512 + col];
                float ua = att[row] * u;
                out[(size_t)row * 512 + col] = fmaf(ua, cal - hv, hv);
            }
        }
    }
#undef ISSUE
#undef MM6
#undef DO_TILE
}

extern "C" void kernel_launch(void* const* d_in, const int* in_sizes, int n_in,
                              void* d_out, int out_size, void* d_ws, size_t ws_size,
                              hipStream_t stream) {
    const float* x    = (const float*)d_in[0];
    const float* h    = (const float*)d_in[1];
    const float* att  = (const float*)d_in[2];
    const float* Wx_r = (const float*)d_in[3];
    const float* b_r  = (const float*)d_in[4];
    const float* Wh_r = (const float*)d_in[5];
    const float* Wx_u = (const float*)d_in[6];
    const float* b_u  = (const float*)d_in[7];
    const float* Wh_u = (const float*)d_in[8];
    const float* Wx_h = (const float*)d_in[9];
    const float* b_h  = (const float*)d_in[10];
    const float* Wh_h = (const float*)d_in[11];
    float* out = (float*)d_out;

    unsigned short* AP = (unsigned short*)d_ws;   // 16 MiB packed [x|h]
    unsigned short* WP = AP + 8388608;            //  3 MiB packed B-hat (R,U,C)

    cvt_all_kernel<<<4864, 256, 0, stream>>>(x, h, AP,
        Wx_r, Wh_r, Wx_u, Wh_u, Wx_h, Wh_h, WP);
    // diagnostics (junk outputs, overwritten by the final correct launch)
    augru_mm<1><<<256, 512, 0, stream>>>(AP, WP, b_r, b_u, b_h, att, h, out);
    augru_mm<2><<<256, 512, 0, stream>>>(AP, WP, b_r, b_u, b_h, att, h, out);
    augru_mm<3><<<256, 512, 0, stream>>>(AP, WP, b_r, b_u, b_h, att, h, out);
    // correct kernel LAST — final d_out is exact
    augru_mm<0><<<256, 512, 0, stream>>>(AP, WP, b_r, b_u, b_h, att, h, out);
}

// Round 9
// 48.718 us; speedup vs baseline: 2.6311x; 2.6311x over previous
//
#include <hip/hip_runtime.h>
#include <hip/hip_bf16.h>

typedef __bf16 bf16x8 __attribute__((ext_vector_type(8)));
typedef float f32x4 __attribute__((ext_vector_type(4)));
typedef unsigned short us8 __attribute__((ext_vector_type(8)));

#define MFMA16 __builtin_amdgcn_mfma_f32_16x16x32_bf16

__device__ __forceinline__ unsigned short f2bf(float f) {
    unsigned int u = __float_as_uint(f);
    u += 0x7fffu + ((u >> 16) & 1u);   // round-to-nearest-even
    return (unsigned short)(u >> 16);
}

__device__ __forceinline__ void gload_lds16(const void* g, void* l) {
    __builtin_amdgcn_global_load_lds(
        (const __attribute__((address_space(1))) unsigned int*)g,
        (__attribute__((address_space(3))) unsigned int*)l, 16, 0, 0);
}

// ============ Pass 1 (fused): pack A' = [x | h] along K' and B-hat panels ====
// Frag = 1024 B = 16 rows x 32 k (lane=(kk>>3)*16+row, 8 contig k per lane).
// A': frag index = mb*32 + kb'  (kb' = kb for x, 16+kb for h), mb 0..511.
// B-hat: 3 buffers (R,U,C) of [nb 0..31][kb' 0..31] frags; kb'<16 from Wx_*,
//        kb'>=16 from Wh_*.
__global__ void cvt_all_kernel(const float* __restrict__ x, const float* __restrict__ h,
                               unsigned short* __restrict__ AP,
                               const float* __restrict__ W0, const float* __restrict__ W1,
                               const float* __restrict__ W2, const float* __restrict__ W3,
                               const float* __restrict__ W4, const float* __restrict__ W5,
                               unsigned short* __restrict__ WP) {
    if (blockIdx.x < 4096) {                         // x,h -> A'
        int c = blockIdx.x * 256 + threadIdx.x;      // 0 .. 2^20-1
        int ih = c >> 19;
        const float* src = ih ? h : x;
        int c2 = c & 524287;
        int mb = c2 >> 10, kb = (c2 >> 6) & 15, lane = c2 & 63;
        int r = lane & 15, ko = lane >> 4;
        const float* p = src + (size_t)(mb * 16 + r) * 512 + kb * 32 + ko * 8;
        float4 v0 = *(const float4*)p;
        float4 v1 = *(const float4*)(p + 4);
        us8 o = { f2bf(v0.x), f2bf(v0.y), f2bf(v0.z), f2bf(v0.w),
                  f2bf(v1.x), f2bf(v1.y), f2bf(v1.z), f2bf(v1.w) };
        *((us8*)AP + ((size_t)(mb * 32 + kb + ih * 16) << 6) + lane) = o;
    } else {                                          // weights -> B-hat
        int c = (blockIdx.x - 4096) * 256 + threadIdx.x;   // 0..196607
        int s = c >> 16, c2 = c & 65535;
        int frag = c2 >> 6, lane = c2 & 63;
        int nb = frag >> 5, kbp = frag & 31;
        const float* Wsrc;
        int kb;
        if (kbp < 16) { kb = kbp;      Wsrc = (s == 0) ? W0 : (s == 1) ? W2 : W4; }
        else          { kb = kbp - 16; Wsrc = (s == 0) ? W1 : (s == 1) ? W3 : W5; }
        int cc = lane & 15, ko = lane >> 4;
        int kbase = kb * 32 + ko * 8;
        us8 o;
#pragma unroll
        for (int e = 0; e < 8; ++e)
            o[e] = f2bf(Wsrc[(size_t)(kbase + e) * 512 + nb * 16 + cc]);
        *((us8*)WP + c) = o;
    }
}

// ============ Pass 2: ZERO-BARRIER fused GEMM + AUGRU epilogue ============
// 8 waves (4M x 2N), wave tile 64r x 32c, block 256r x 64c, BK=32, 32 K-tiles.
// Per-wave-private staging: A via global_load_lds into a private 8KB dbuf
// (64KB LDS total), B via global->VGPR, both 2 tiles deep. All sync is
// per-wave counted vmcnt/lgkmcnt — NO s_barrier in the entire kernel
// (round-8 ablation: barrier-free full-work variant ran ~8x faster).
__global__ __launch_bounds__(512, 2) void augru_mm(
    const unsigned short* __restrict__ AP_,
    const unsigned short* __restrict__ WP_,   // 3 x 1 MiB (R,U,C)
    const float* __restrict__ b_r, const float* __restrict__ b_u, const float* __restrict__ b_h,
    const float* __restrict__ att, const float* __restrict__ h32,
    float* __restrict__ out) {
    __shared__ unsigned char sA[65536];       // [wave 8][buf 2][mf 4][1KB]
    const unsigned char* APb = (const unsigned char*)AP_;
    const unsigned char* WPb = (const unsigned char*)WP_;

    const int t0 = threadIdx.x, wv = t0 >> 6, lane = t0 & 63;
    const int laneoff = lane * 16;

    // bijective XCD swizzle: XCD x owns Wid in [32x, 32x+32) -> 4 m-panels
    const int bid = blockIdx.x;               // 0..255
    const int Wid = (bid & 7) * 32 + (bid >> 3);
    const int mblk = Wid >> 3, nblk = Wid & 7;
    const int wr = wv >> 1, wc = wv & 1;      // 4M x 2N wave grid

    f32x4 accR[4][2] = {}, accU[4][2] = {}, accXH[4][2] = {}, accHH[4][2] = {};

    // A: per-lane global src, wave-uniform LDS dst (private region)
    const unsigned char* gA[4];
    unsigned dsA[4];
#pragma unroll
    for (int mf = 0; mf < 4; ++mf) {
        int mb = mblk * 16 + wr * 4 + mf;
        gA[mf] = APb + ((size_t)(mb * 32) << 10) + laneoff;
        dsA[mf] = (unsigned)(wv * 8192 + mf * 1024);
    }
    // B: per-lane global src (3 sets x 2 nf)
    const unsigned char* gB[3][2];
#pragma unroll
    for (int s = 0; s < 3; ++s)
#pragma unroll
        for (int nf = 0; nf < 2; ++nf)
            gB[s][nf] = WPb + (size_t)s * 1048576 +
                        ((size_t)((nblk * 4 + wc * 2 + nf) * 32) << 10) + laneoff;

    bf16x8 a[4], b0[3][2], b1[3][2];

    // prologue: A(0)->buf0, B(0)->b0, A(1)->buf1, B(1)->b1; empty-asm fences
    // pin group issue-order so vmcnt(10) retires exactly {A(t),B(t)}.
#pragma unroll
    for (int mf = 0; mf < 4; ++mf)
        gload_lds16(gA[mf], (unsigned char*)sA + dsA[mf]);
    asm volatile("" ::: "memory");
#pragma unroll
    for (int s = 0; s < 3; ++s)
#pragma unroll
        for (int nf = 0; nf < 2; ++nf)
            b0[s][nf] = *(const bf16x8*)(gB[s][nf]);
    asm volatile("" ::: "memory");
#pragma unroll
    for (int mf = 0; mf < 4; ++mf)
        gload_lds16(gA[mf] + 1024, (unsigned char*)sA + dsA[mf] + 4096);
    asm volatile("" ::: "memory");
#pragma unroll
    for (int s = 0; s < 3; ++s)
#pragma unroll
        for (int nf = 0; nf < 2; ++nf)
            b1[s][nf] = *(const bf16x8*)(gB[s][nf] + 1024);

// body(T): wait tile-T group; ds_read A; retire reads; refill buf with T+2;
// 24 MFMAs; load B(T+2). P = phase (buf/regset), VMC = vmcnt literal.
#define BODY(T, P, BREG, ACCC, VMC, PF) { \
    asm volatile("s_waitcnt vmcnt(" VMC ")" ::: "memory"); \
    _Pragma("unroll") for (int mf = 0; mf < 4; ++mf) \
        a[mf] = *(const bf16x8*)((const unsigned char*)sA + dsA[mf] + (P) * 4096 + laneoff); \
    asm volatile("s_waitcnt lgkmcnt(0)" ::: "memory"); \
    if (PF) { _Pragma("unroll") for (int mf = 0; mf < 4; ++mf) \
        gload_lds16(gA[mf] + ((size_t)((T) + 2) << 10), \
                    (unsigned char*)sA + dsA[mf] + (P) * 4096); } \
    __builtin_amdgcn_s_setprio(1); \
    _Pragma("unroll") for (int mf = 0; mf < 4; ++mf) \
      _Pragma("unroll") for (int nf = 0; nf < 2; ++nf) { \
        accR[mf][nf] = MFMA16(a[mf], BREG[0][nf], accR[mf][nf], 0, 0, 0); \
        accU[mf][nf] = MFMA16(a[mf], BREG[1][nf], accU[mf][nf], 0, 0, 0); \
        ACCC[mf][nf] = MFMA16(a[mf], BREG[2][nf], ACCC[mf][nf], 0, 0, 0); } \
    __builtin_amdgcn_s_setprio(0); \
    if (PF) { _Pragma("unroll") for (int s = 0; s < 3; ++s) \
      _Pragma("unroll") for (int nf = 0; nf < 2; ++nf) \
        BREG[s][nf] = *(const bf16x8*)(gB[s][nf] + ((size_t)((T) + 2) << 10)); } \
}

#pragma unroll 1
    for (int i = 0; i < 8; ++i) {             // tiles 0..15: x-half -> accXH
        const int te = 2 * i;
        BODY(te,     0, b0, accXH, "10", true)
        BODY(te + 1, 1, b1, accXH, "10", true)
    }
#pragma unroll 1
    for (int i = 8; i < 15; ++i) {            // tiles 16..29: h-half -> accHH
        const int te = 2 * i;
        BODY(te,     0, b0, accHH, "10", true)
        BODY(te + 1, 1, b1, accHH, "10", true)
    }
    BODY(30, 0, b0, accHH, "10", false)       // tile 30 (no prefetch)
    BODY(31, 1, b1, accHH, "0",  false)       // tile 31 (drain)

    // epilogue: C/D layout col=lane&15, row=(lane>>4)*4+reg  [m89-verified]
    const int lr = lane & 15, lg = lane >> 4;
#pragma unroll
    for (int nf = 0; nf < 2; ++nf) {
        const int col = nblk * 64 + wc * 32 + nf * 16 + lr;
        const float br = b_r[col], bu = b_u[col], bh = b_h[col];
#pragma unroll
        for (int mf = 0; mf < 4; ++mf) {
            const int rowb = mblk * 256 + wr * 64 + mf * 16 + lg * 4;
#pragma unroll
            for (int q = 0; q < 4; ++q) {
                const int row = rowb + q;
                float r = 1.f / (1.f + __expf(-(accR[mf][nf][q] + br)));
                float u = 1.f / (1.f + __expf(-(accU[mf][nf][q] + bu)));
                float ph = accXH[mf][nf][q] + bh + r * accHH[mf][nf][q];
                ph = fminf(fmaxf(ph, -15.f), 15.f);
                float e = __expf(2.f * ph);
                float cal = (e - 1.f) / (e + 1.f);
                float hv = h32[(size_t)row * 512 + col];
                float ua = att[row] * u;
                out[(size_t)row * 512 + col] = fmaf(ua, cal - hv, hv);
            }
        }
    }
#undef BODY
}

extern "C" void kernel_launch(void* const* d_in, const int* in_sizes, int n_in,
                              void* d_out, int out_size, void* d_ws, size_t ws_size,
                              hipStream_t stream) {
    const float* x    = (const float*)d_in[0];
    const float* h    = (const float*)d_in[1];
    const float* att  = (const float*)d_in[2];
    const float* Wx_r = (const float*)d_in[3];
    const float* b_r  = (const float*)d_in[4];
    const float* Wh_r = (const float*)d_in[5];
    const float* Wx_u = (const float*)d_in[6];
    const float* b_u  = (const float*)d_in[7];
    const float* Wh_u = (const float*)d_in[8];
    const float* Wx_h = (const float*)d_in[9];
    const float* b_h  = (const float*)d_in[10];
    const float* Wh_h = (const float*)d_in[11];
    float* out = (float*)d_out;

    unsigned short* AP = (unsigned short*)d_ws;   // 16 MiB packed [x|h]
    unsigned short* WP = AP + 8388608;            //  3 MiB packed B-hat (R,U,C)

    cvt_all_kernel<<<4864, 256, 0, stream>>>(x, h, AP,
        Wx_r, Wh_r, Wx_u, Wh_u, Wx_h, Wh_h, WP);
    augru_mm<<<256, 512, 0, stream>>>(AP, WP, b_r, b_u, b_h, att, h, out);
}